// Round 12
// baseline (126.937 us; speedup 1.0000x reference)
//
#include <hip/hip_runtime.h>
#include <hip/hip_bf16.h>

typedef __attribute__((ext_vector_type(8))) __bf16 bf16x8;
typedef __attribute__((ext_vector_type(4))) float f32x4;
typedef unsigned short u16;

#define NB 8192
#define ND 128
#define NEGINF (-__builtin_inff())
#define POSINF (__builtin_inff())

__device__ inline u16 f2b(float f){
  __hip_bfloat16 h = __float2bfloat16(f);
  return *reinterpret_cast<u16*>(&h);
}

// ---- prep: fp32 -> bf16, colp[row] = (sq, p=1/(1-sq), sq*p, lab_bits) ------
// also zeroes the final-reduction cells (graph-replay-safe: prep runs first
// every iteration).
extern "C" __global__ __launch_bounds__(256)
void prep_k(const float* __restrict__ x, const int* __restrict__ lab,
            u16* __restrict__ xb, float4* __restrict__ colp,
            float* __restrict__ gred, unsigned int* __restrict__ done)
{
  if (blockIdx.x == 0 && threadIdx.x == 0){
    gred[0] = 0.0f; gred[1] = 0.0f; *done = 0u;
  }
  const int tid = blockIdx.x * 256 + threadIdx.x;
  const int row = tid >> 5;           // 32 threads per row
  const int sub = tid & 31;
  const float4 v = reinterpret_cast<const float4*>(x)[row * 32 + sub];
  float s = v.x*v.x + v.y*v.y + v.z*v.z + v.w*v.w;
  #pragma unroll
  for (int m = 1; m < 32; m <<= 1) s += __shfl_xor(s, m, 32);
  ushort4 o;
  o.x = f2b(v.x); o.y = f2b(v.y); o.z = f2b(v.z); o.w = f2b(v.w);
  reinterpret_cast<ushort4*>(xb)[row * 32 + sub] = o;
  if (sub == 0){
    const float p = 1.0f / (1.0f - s);
    colp[row] = make_float4(s, p, s * p, __int_as_float(lab[row]));
  }
}

// ---- main: bf16 MFMA gram tiles, SYMMETRY-HALVED, ATOMIC-FREE --------------
// 544 blocks launched (upper-triangle tiles only), linear id -> (rb, cb) via
// cum(cb) = 2cb(cb+1). Each tile serves BOTH triangles:
//   direct   : row i over cols j, u_d = d2*p_j -> registers, stored to
//              dpos/dneg[cb][row] (disjoint per cb, plain stores).
//   transpose: col j over rows i, u_t = d2*p_i -> per-phase quad-reduce,
//              ACCUMULATED IN LDS (each wave owns its [wid][512] slice, no
//              races), cross-wave max after the main loop, plain store to
//              tpos/tneg[rb][col] (disjoint per rb).
// R11 LESSON: device-scope atomics on hot arrays = 24 MB writeback + serial-
// ization (+12us). This version has ZERO atomics in gram_k.
// d2 = max(sq_i+sq_j-2g, 1e-30) matches ref (fin's 1e-7 t-clamp absorbs it).
// Coverage: (i,j) hits direct if chunk(j) >= band(i)/4, else transpose of
// the mirrored tile; duplicates idempotent under max/min. Verified r11.
// Carried: 2-phase LDS dbuf (r2/r3), rolled loop (r3), incremental pointers
// (r6), uniform-wid s_cbranch (r7), (256,3) no-spill budget (r3/r8).
extern "C" __global__ __launch_bounds__(256, 3)
void gram_k(const u16* __restrict__ xb, const float4* __restrict__ colp,
            float* __restrict__ dpos, float* __restrict__ dneg,
            float* __restrict__ tpos, float* __restrict__ tneg)
{
  // linear block id -> (rb, cb): cb such that 2cb(cb+1) <= l < 2(cb+1)(cb+2)
  const int l = blockIdx.x;
  int cb = 0;
  while (2 * (cb + 1) * (cb + 2) <= l) ++cb;
  const int rb = l - 2 * cb * (cb + 1);

  __shared__ u16 Bt[2][64 * 128];   // 2 x 16 KB double buffer, 256B/col,
                                    // 16B chunks XOR-swizzled by col&15
  __shared__ float tlp[4][512];     // 8 KB: per-wave transpose pos partials
  __shared__ float tln[4][512];     // 8 KB: per-wave transpose neg partials
  const int wid  = __builtin_amdgcn_readfirstlane(threadIdx.x >> 6);
  const int lane = threadIdx.x & 63;
  const int m16  = lane & 15;
  const int quad = lane >> 4;
  const int R0  = rb * 128;
  const int C0  = cb * 512;
  const int WR0 = R0 + wid * 32;     // wave-uniform (SGPR)

  // A fragments in registers: A[m=lane&15][k=quad*8+j]
  bf16x8 afrag[2][4];
  #pragma unroll
  for (int mt = 0; mt < 2; ++mt){
    const u16* arow = xb + (WR0 + mt*16 + m16) * ND;
    #pragma unroll
    for (int ks = 0; ks < 4; ++ks)
      afrag[mt][ks] = *reinterpret_cast<const bf16x8*>(arow + ks*32 + quad*8);
  }

  // per-row (C/D row = quad*4 + r) params: sq_i, p_i, label
  float sqi[8], pii[8]; int labi[8];
  #pragma unroll
  for (int mt = 0; mt < 2; ++mt)
    #pragma unroll
    for (int r = 0; r < 4; ++r){
      const float4 cp = colp[WR0 + mt*16 + quad*4 + r];
      sqi[mt*4+r]  = cp.x;
      pii[mt*4+r]  = cp.y;
      labi[mt*4+r] = __float_as_int(cp.w);
    }

  float vpos[8], vneg[8];
  #pragma unroll
  for (int i = 0; i < 8; ++i){ vpos[i] = NEGINF; vneg[i] = POSINF; }

  // Per-thread staging base pointers, computed ONCE (r6).
  const u16* sp0 = xb + (C0 + wid*16 + 0*4 + quad) * ND + (m16 ^ ((0*4 + quad) & 15)) * 8;
  const u16* sp1 = xb + (C0 + wid*16 + 1*4 + quad) * ND + (m16 ^ ((1*4 + quad) & 15)) * 8;
  const u16* sp2 = xb + (C0 + wid*16 + 2*4 + quad) * ND + (m16 ^ ((2*4 + quad) & 15)) * 8;
  const u16* sp3 = xb + (C0 + wid*16 + 3*4 + quad) * ND + (m16 ^ ((3*4 + quad) & 15)) * 8;
  const float4* cpp = colp + C0 + m16;

  auto stage = [&](int b){
    __builtin_amdgcn_global_load_lds(
        (__attribute__((address_space(1))) void*)sp0,
        (__attribute__((address_space(3))) void*)(&Bt[b][(wid*4 + 0) * 512]), 16, 0, 0);
    __builtin_amdgcn_global_load_lds(
        (__attribute__((address_space(1))) void*)sp1,
        (__attribute__((address_space(3))) void*)(&Bt[b][(wid*4 + 1) * 512]), 16, 0, 0);
    __builtin_amdgcn_global_load_lds(
        (__attribute__((address_space(1))) void*)sp2,
        (__attribute__((address_space(3))) void*)(&Bt[b][(wid*4 + 2) * 512]), 16, 0, 0);
    __builtin_amdgcn_global_load_lds(
        (__attribute__((address_space(1))) void*)sp3,
        (__attribute__((address_space(3))) void*)(&Bt[b][(wid*4 + 3) * 512]), 16, 0, 0);
    sp0 += 64 * ND; sp1 += 64 * ND; sp2 += 64 * ND; sp3 += 64 * ND;
  };

  auto compute = [&](int s, int b){
    const int CT0 = C0 + s * 64;
    f32x4 acc[2][4];
    #pragma unroll
    for (int mt = 0; mt < 2; ++mt)
      #pragma unroll
      for (int nt = 0; nt < 4; ++nt){
        f32x4 z = {0.f, 0.f, 0.f, 0.f};
        acc[mt][nt] = z;
      }

    #pragma unroll
    for (int ks = 0; ks < 4; ++ks){
      const int t = ks * 4 + quad;                 // 16B chunk index in col
      const u16* bb = &Bt[b][0] + m16 * 128 + ((t ^ m16) * 8);
      #pragma unroll
      for (int nt = 0; nt < 4; ++nt){
        const bf16x8 bfrag = *reinterpret_cast<const bf16x8*>(bb + nt * 2048);
        acc[0][nt] = __builtin_amdgcn_mfma_f32_16x16x32_bf16(afrag[0][ks], bfrag, acc[0][nt], 0, 0, 0);
        acc[1][nt] = __builtin_amdgcn_mfma_f32_16x16x32_bf16(afrag[1][ks], bfrag, acc[1][nt], 0, 0, 0);
      }
    }

    // epilogue: d2 = max(sq_i+sq_j-2g, 1e-30); u_d = d2*p_j -> row i (regs);
    // u_t = d2*p_i -> col j (quad-reduce -> per-wave LDS slice).
    float tp[4], tn[4];
    #pragma unroll
    for (int nt = 0; nt < 4; ++nt){
      const float4 cp = cpp[nt * 16];
      const float sqj  = cp.x;
      const float pj   = cp.y;
      const int   labj = __float_as_int(cp.w);
      float tpn = NEGINF, tnn = POSINF;
      #pragma unroll
      for (int mt = 0; mt < 2; ++mt){
        const bool tilediag = (WR0 + mt*16) == (CT0 + nt*16);
        if (!tilediag){
          #pragma unroll
          for (int r = 0; r < 4; ++r){
            const int idx = mt*4 + r;
            float d2 = fmaf(-2.0f, acc[mt][nt][r], sqi[idx] + sqj);
            d2 = fmaxf(d2, 1e-30f);
            const float ud = d2 * pj;
            const float ut = d2 * pii[idx];
            const bool sm = (labi[idx] == labj);
            vpos[idx] = fmaxf(vpos[idx], sm ? ud : NEGINF);
            vneg[idx] = fminf(vneg[idx], sm ? POSINF : ud);
            tpn = fmaxf(tpn, sm ? ut : NEGINF);
            tnn = fminf(tnn, sm ? POSINF : ut);
          }
        } else {
          #pragma unroll
          for (int r = 0; r < 4; ++r){
            const int idx = mt*4 + r;
            float d2 = fmaf(-2.0f, acc[mt][nt][r], sqi[idx] + sqj);
            d2 = fmaxf(d2, 1e-30f);
            const float ud = d2 * pj;
            const float ut = d2 * pii[idx];
            const bool sm = (labi[idx] == labj);
            const bool dg = (m16 == quad*4 + r);
            const bool ps = sm && !dg;
            vpos[idx] = fmaxf(vpos[idx], ps ? ud : NEGINF);
            vneg[idx] = fminf(vneg[idx], sm ? POSINF : ud);
            tpn = fmaxf(tpn, ps ? ut : NEGINF);
            tnn = fminf(tnn, sm ? POSINF : ut);
          }
        }
      }
      tp[nt] = tpn; tn[nt] = tnn;
    }
    // transpose finish for this phase: reduce over quads, then lane
    // (quad,m16) holds col CT0+lane; write to this wave's LDS slice.
    #pragma unroll
    for (int nt = 0; nt < 4; ++nt){
      tp[nt] = fmaxf(tp[nt], __shfl_xor(tp[nt], 16, 64));
      tp[nt] = fmaxf(tp[nt], __shfl_xor(tp[nt], 32, 64));
      tn[nt] = fminf(tn[nt], __shfl_xor(tn[nt], 16, 64));
      tn[nt] = fminf(tn[nt], __shfl_xor(tn[nt], 32, 64));
    }
    const float wp = (quad == 0) ? tp[0] : (quad == 1) ? tp[1]
                   : (quad == 2) ? tp[2] : tp[3];
    const float wn = (quad == 0) ? tn[0] : (quad == 1) ? tn[1]
                   : (quad == 2) ? tn[2] : tn[3];
    tlp[wid][s * 64 + lane] = wp;
    tln[wid][s * 64 + lane] = wn;
    cpp += 64;                            // next half-tile's column params
  };

  // pipelined main loop, ROLLED (r3): half-tiles {2ss,2ss+1} in bufs {0,1}.
  stage(0);                              // s=0 -> buf0
  __syncthreads();                       // drains vmcnt(0): tile 0 ready
  #pragma unroll 1
  for (int ss = 0; ss < 4; ++ss){
    const int s0 = ss * 2;
    stage(1);                            // s0+1 -> buf1
    compute(s0, 0);
    __syncthreads();                     // buf1 staged; buf0 consumed
    if (ss < 3) stage(0);                // s0+2 -> buf0
    compute(s0 + 1, 1);
    if (ss < 3) __syncthreads();         // buf0 staged; buf1 consumed
  }

  // direct finish: row i lives in the 16 lanes of one quad-group
  #pragma unroll
  for (int i = 0; i < 8; ++i){
    #pragma unroll
    for (int m = 1; m < 16; m <<= 1){
      vpos[i] = fmaxf(vpos[i], __shfl_xor(vpos[i], m, 16));
      vneg[i] = fminf(vneg[i], __shfl_xor(vneg[i], m, 16));
    }
  }
  if (m16 == 0){
    #pragma unroll
    for (int i = 0; i < 8; ++i){
      const int row = WR0 + (i >> 2)*16 + quad*4 + (i & 3);
      dpos[cb * NB + row] = vpos[i];
      dneg[cb * NB + row] = vneg[i];
    }
  }

  // transpose finish: cross-wave max/min over the 4 LDS slices, plain
  // coalesced store to this rb's slice (disjoint across blocks).
  __syncthreads();
  #pragma unroll
  for (int c = 0; c < 2; ++c){
    const int col = c * 256 + threadIdx.x;
    const float vp = fmaxf(fmaxf(tlp[0][col], tlp[1][col]),
                           fmaxf(tlp[2][col], tlp[3][col]));
    const float vn = fminf(fminf(tln[0][col], tln[1][col]),
                           fminf(tln[2][col], tln[3][col]));
    tpos[rb * NB + C0 + col] = vp;
    tneg[rb * NB + C0 + col] = vn;
  }
}

// ---- finalize (fused): 64 blocks x 128 rows -> atomic finish ---------------
// For row r (band rbr = r>>7, chunk cbr = r>>9):
//   direct partials    dpos[cb][r] valid for cb in [rbr>>2, 16)
//   transpose partials tpos[rb][r] valid for rb in [0, 4*cbr+3]
extern "C" __global__ __launch_bounds__(128)
void fin_k(const float* __restrict__ dpos, const float* __restrict__ dneg,
           const float* __restrict__ tpos, const float* __restrict__ tneg,
           const float4* __restrict__ colp, float* __restrict__ gred,
           unsigned int* __restrict__ done, float* __restrict__ out)
{
  const int row = blockIdx.x * 128 + threadIdx.x;
  const int rbr = row >> 7;
  const int cbr = row >> 9;
  float up = NEGINF, un = POSINF;
  for (int cb = rbr >> 2; cb < 16; ++cb){
    up = fmaxf(up, dpos[cb * NB + row]);
    un = fminf(un, dneg[cb * NB + row]);
  }
  const int rbmax = cbr * 4 + 3;        // <= 63
  for (int rb = 0; rb <= rbmax; ++rb){
    up = fmaxf(up, tpos[rb * NB + row]);
    un = fminf(un, tneg[rb * NB + row]);
  }
  const bool hp = (up > NEGINF);
  const bool hn = (un < POSINF);
  const float pi = colp[row].y;
  float dp = 0.0f, dn = 0.0f;
  // arccosh(1+t) = log1p(t + sqrt(t*(t+2))), t clamped at 1e-7 (matches ref)
  if (hp){ float t = fmaxf(2.0f * up * pi, 1e-7f); dp = log1pf(t + sqrtf(t * (t + 2.0f))); }
  if (hn){ float t = fmaxf(2.0f * un * pi, 1e-7f); dn = log1pf(t + sqrtf(t * (t + 2.0f))); }
  float lsum = (hp && hn) ? fmaxf(dp - dn + 0.5f, 0.0f) : 0.0f;
  float lcnt = (hp && hn) ? 1.0f : 0.0f;
  #pragma unroll
  for (int m = 1; m < 64; m <<= 1){
    lsum += __shfl_xor(lsum, m, 64);
    lcnt += __shfl_xor(lcnt, m, 64);
  }
  __shared__ float2 s_p[2];
  if ((threadIdx.x & 63) == 0) s_p[threadIdx.x >> 6] = make_float2(lsum, lcnt);
  __syncthreads();
  if (threadIdx.x == 0){
    const float bs = s_p[0].x + s_p[1].x;
    const float bc = s_p[0].y + s_p[1].y;
    atomicAdd(&gred[0], bs);
    atomicAdd(&gred[1], bc);
    __threadfence();
    const unsigned int prev = atomicAdd(done, 1u);
    if (prev == 63u){                      // last block: all adds visible
      __threadfence();
      const float s = atomicAdd(&gred[0], 0.0f);   // read via atomic (L2)
      const float c = atomicAdd(&gred[1], 0.0f);
      out[0] = (c > 0.0f) ? (s / c) : 0.0f;
    }
  }
}

extern "C" void kernel_launch(void* const* d_in, const int* in_sizes, int n_in,
                              void* d_out, int out_size, void* d_ws, size_t ws_size,
                              hipStream_t stream)
{
  const float* x  = (const float*)d_in[0];
  const int* lab  = (const int*)d_in[1];
  char* ws = (char*)d_ws;
  size_t off = 0;
  u16*    xb   = (u16*)(ws + off);   off += (size_t)2*1024*1024;   // 2 MB
  float4* colp = (float4*)(ws + off); off += 128*1024;             // 128 KB
  float*  dpos = (float*)(ws + off); off += (size_t)16*NB*4;       // 512 KB
  float*  dneg = (float*)(ws + off); off += (size_t)16*NB*4;       // 512 KB
  float*  tpos = (float*)(ws + off); off += (size_t)64*NB*4;       // 2 MB
  float*  tneg = (float*)(ws + off); off += (size_t)64*NB*4;       // 2 MB
  float*  gred = (float*)(ws + off); off += 64;                    // 8 B
  unsigned int* done = (unsigned int*)(ws + off);                  // 4 B

  hipLaunchKernelGGL(prep_k, dim3(1024), dim3(256), 0, stream, x, lab, xb, colp,
                     gred, done);
  hipLaunchKernelGGL(gram_k, dim3(544), dim3(256), 0, stream,
                     xb, colp, dpos, dneg, tpos, tneg);
  hipLaunchKernelGGL(fin_k, dim3(64), dim3(128), 0, stream, dpos, dneg,
                     tpos, tneg, colp, gred, done, (float*)d_out);
}

// Round 13
// 107.728 us; speedup vs baseline: 1.1783x; 1.1783x over previous
//
#include <hip/hip_runtime.h>
#include <hip/hip_bf16.h>

typedef __attribute__((ext_vector_type(8))) __bf16 bf16x8;
typedef __attribute__((ext_vector_type(4))) float f32x4;
typedef unsigned short u16;

#define NB 8192
#define ND 128
#define NCHUNK 16
#define NEGINF (-__builtin_inff())
#define POSINF (__builtin_inff())

__device__ inline u16 f2b(float f){
  __hip_bfloat16 h = __float2bfloat16(f);
  return *reinterpret_cast<u16*>(&h);
}

// ---- prep: fp32 -> bf16, colp[row] = (sq, p=1/(1-sq), sq*p, lab_bits) ------
// also zeroes the final-reduction cells so fin_k's atomic finish is
// graph-replay-safe (stream order: prep -> gram -> fin every iteration).
extern "C" __global__ __launch_bounds__(256)
void prep_k(const float* __restrict__ x, const int* __restrict__ lab,
            u16* __restrict__ xb, float4* __restrict__ colp,
            float* __restrict__ gred, unsigned int* __restrict__ done)
{
  if (blockIdx.x == 0 && threadIdx.x == 0){
    gred[0] = 0.0f; gred[1] = 0.0f; *done = 0u;
  }
  const int tid = blockIdx.x * 256 + threadIdx.x;
  const int row = tid >> 5;           // 32 threads per row
  const int sub = tid & 31;
  const float4 v = reinterpret_cast<const float4*>(x)[row * 32 + sub];
  float s = v.x*v.x + v.y*v.y + v.z*v.z + v.w*v.w;
  #pragma unroll
  for (int m = 1; m < 32; m <<= 1) s += __shfl_xor(s, m, 32);
  ushort4 o;
  o.x = f2b(v.x); o.y = f2b(v.y); o.z = f2b(v.z); o.w = f2b(v.w);
  reinterpret_cast<ushort4*>(xb)[row * 32 + sub] = o;
  if (sub == 0){
    const float p = 1.0f / (1.0f - s);
    colp[row] = make_float4(s, p, s * p, __int_as_float(lab[row]));
  }
}

// ---- main: bf16 MFMA gram tiles + streaming row max/min --------------------
// grid (64, 16): x = 128-row tile, y = 512-col chunk. 4 waves x 32 rows.
// R11/R12 LESSON: symmetry-halving loses — the epilogue (not MFMA) is the
// marginal cost; doubling it to serve both triangles costs more than the
// 47% MFMA/staging saved. Full-tile r7 algorithm restored.
// ROUND-13 (T4, m218/m233): counted-vmcnt pipeline. The 2-phase
// __syncthreads loop drains vmcnt(0) every phase -> stage+drain+barrier is
// the critical path (pipes individually 10-17us, wall 41.4us, busy%s sum
// ~80% non-overlapped). Now: 3 LDS buffers, 2 stages in flight, per phase
//   stage(s+2) -> compute(s) -> s_waitcnt vmcnt(4) -> raw s_barrier
// vmcnt(4) = this wave's stage-(s+1) loads done, stage-(s+2)'s 4 still
// flying (never drain to 0 mid-loop). Barrier joins waves -> buffer s+1
// collectively staged. Overwrite-safe: buf (s+2)%3 was last read in
// compute(s-1), which precedes this barrier for all waves.
// Carried: incremental pointers (r6), uniform-wid s_cbranch (r7),
// (256,3) no-spill budget (r3/r8), XOR-swizzled staging (r0).
extern "C" __global__ __launch_bounds__(256, 3)
void gram_k(const u16* __restrict__ xb, const float4* __restrict__ colp,
            float* __restrict__ ppos, float* __restrict__ pneg)
{
  __shared__ u16 Bt[3][64 * 128];   // 3 x 16 KB ring buffer, 256B/col,
                                    // 16B chunks XOR-swizzled by col&15
  const int wid  = __builtin_amdgcn_readfirstlane(threadIdx.x >> 6);
  const int lane = threadIdx.x & 63;
  const int m16  = lane & 15;
  const int quad = lane >> 4;
  const int R0  = blockIdx.x * 128;
  const int C0  = blockIdx.y * 512;
  const int WR0 = R0 + wid * 32;     // wave-uniform (SGPR)

  // A fragments in registers: A[m=lane&15][k=quad*8+j]
  bf16x8 afrag[2][4];
  #pragma unroll
  for (int mt = 0; mt < 2; ++mt){
    const u16* arow = xb + (WR0 + mt*16 + m16) * ND;
    #pragma unroll
    for (int ks = 0; ks < 4; ++ks)
      afrag[mt][ks] = *reinterpret_cast<const bf16x8*>(arow + ks*32 + quad*8);
  }

  // per-row (C/D row = quad*4 + r) params
  float sqi[8]; int labi[8];
  #pragma unroll
  for (int mt = 0; mt < 2; ++mt)
    #pragma unroll
    for (int r = 0; r < 4; ++r){
      const float4 cp = colp[WR0 + mt*16 + quad*4 + r];
      sqi[mt*4+r]  = cp.x;
      labi[mt*4+r] = __float_as_int(cp.w);
    }

  float vpos[8], vneg[8];
  #pragma unroll
  for (int i = 0; i < 8; ++i){ vpos[i] = NEGINF; vneg[i] = POSINF; }

  // Per-thread staging base pointers, computed ONCE (r6). For chunk c (0..3):
  // brow(c) = wid*16 + c*4 + quad; src(c) = m16 ^ (brow(c) & 15).
  // Advanced by +64*ND after each stage call (stage order s = 0..7).
  const u16* sp0 = xb + (C0 + wid*16 + 0*4 + quad) * ND + (m16 ^ ((0*4 + quad) & 15)) * 8;
  const u16* sp1 = xb + (C0 + wid*16 + 1*4 + quad) * ND + (m16 ^ ((1*4 + quad) & 15)) * 8;
  const u16* sp2 = xb + (C0 + wid*16 + 2*4 + quad) * ND + (m16 ^ ((2*4 + quad) & 15)) * 8;
  const u16* sp3 = xb + (C0 + wid*16 + 3*4 + quad) * ND + (m16 ^ ((3*4 + quad) & 15)) * 8;
  // epilogue column-param pointer: advanced by +64 per compute (s = 0..7)
  const float4* cpp = colp + C0 + m16;

  // stage 64 B-rows (16 KB) into ring buffer b; advance base pointers.
  auto stage = [&](int b){
    u16* dst = &Bt[b][0] + (wid * 4) * 512;
    __builtin_amdgcn_global_load_lds(
        (__attribute__((address_space(1))) void*)sp0,
        (__attribute__((address_space(3))) void*)(dst + 0 * 512), 16, 0, 0);
    __builtin_amdgcn_global_load_lds(
        (__attribute__((address_space(1))) void*)sp1,
        (__attribute__((address_space(3))) void*)(dst + 1 * 512), 16, 0, 0);
    __builtin_amdgcn_global_load_lds(
        (__attribute__((address_space(1))) void*)sp2,
        (__attribute__((address_space(3))) void*)(dst + 2 * 512), 16, 0, 0);
    __builtin_amdgcn_global_load_lds(
        (__attribute__((address_space(1))) void*)sp3,
        (__attribute__((address_space(3))) void*)(dst + 3 * 512), 16, 0, 0);
    sp0 += 64 * ND; sp1 += 64 * ND; sp2 += 64 * ND; sp3 += 64 * ND;
  };

  auto compute = [&](int s, int b){
    const int CT0 = C0 + s * 64;
    f32x4 acc[2][4];
    #pragma unroll
    for (int mt = 0; mt < 2; ++mt)
      #pragma unroll
      for (int nt = 0; nt < 4; ++nt){
        f32x4 z = {0.f, 0.f, 0.f, 0.f};
        acc[mt][nt] = z;
      }

    #pragma unroll
    for (int ks = 0; ks < 4; ++ks){
      const int t = ks * 4 + quad;                 // 16B chunk index in col
      const u16* bb = &Bt[b][0] + m16 * 128 + ((t ^ m16) * 8);
      #pragma unroll
      for (int nt = 0; nt < 4; ++nt){
        const bf16x8 bfrag = *reinterpret_cast<const bf16x8*>(bb + nt * 2048);
        acc[0][nt] = __builtin_amdgcn_mfma_f32_16x16x32_bf16(afrag[0][ks], bfrag, acc[0][nt], 0, 0, 0);
        acc[1][nt] = __builtin_amdgcn_mfma_f32_16x16x32_bf16(afrag[1][ks], bfrag, acc[1][nt], 0, 0, 0);
      }
    }

    // epilogue: u = (sq_i + sq_j - 2g) * p_j  (no interior clamp; fin clamps)
    // colp via incremental pointer; tilediag SGPR-uniform -> s_cbranch.
    #pragma unroll
    for (int nt = 0; nt < 4; ++nt){
      const float4 cp = cpp[nt * 16];
      const float pj   = cp.y;
      const float spj  = cp.z;
      const int   labj = __float_as_int(cp.w);
      const float n2pj = -2.0f * pj;
      #pragma unroll
      for (int mt = 0; mt < 2; ++mt){
        const bool tilediag = (WR0 + mt*16) == (CT0 + nt*16);
        if (!tilediag){
          #pragma unroll
          for (int r = 0; r < 4; ++r){
            const int idx = mt*4 + r;
            const float u = fmaf(n2pj, acc[mt][nt][r], fmaf(sqi[idx], pj, spj));
            const bool sm = (labi[idx] == labj);
            vpos[idx] = fmaxf(vpos[idx], sm ? u : NEGINF);
            vneg[idx] = fminf(vneg[idx], sm ? POSINF : u);
          }
        } else {
          #pragma unroll
          for (int r = 0; r < 4; ++r){
            const int idx = mt*4 + r;
            const float u = fmaf(n2pj, acc[mt][nt][r], fmaf(sqi[idx], pj, spj));
            const bool sm = (labi[idx] == labj);
            const bool dg = (m16 == quad*4 + r);
            vpos[idx] = fmaxf(vpos[idx], (sm && !dg) ? u : NEGINF);
            vneg[idx] = fminf(vneg[idx], sm ? POSINF : u);
          }
        }
      }
    }
    cpp += 64;                            // next half-tile's column params
  };

  // counted-vmcnt pipeline: 2 stages in flight, raw barriers, never
  // vmcnt(0) mid-loop. stage s -> buffer s%3; compute s reads buffer s%3.
  stage(0);                              // -> buf0 (4 loads)
  stage(1);                              // -> buf1 (8 in flight)
  asm volatile("s_waitcnt vmcnt(4)" ::: "memory");   // buf0 staged
  __builtin_amdgcn_s_barrier();
  int cbuf = 0, sbuf = 2;
  #pragma unroll 1
  for (int s = 0; s < 8; ++s){
    if (s < 6){ stage(sbuf); sbuf = (sbuf == 2) ? 0 : sbuf + 1; }
    compute(s, cbuf);
    cbuf = (cbuf == 2) ? 0 : cbuf + 1;
    if (s < 7){
      if (s < 6) asm volatile("s_waitcnt vmcnt(4)" ::: "memory"); // s+1 staged,
      else       asm volatile("s_waitcnt vmcnt(0)" ::: "memory"); // tail drain
      __builtin_amdgcn_s_barrier();      // all waves' s+1 loads landed;
    }                                    // buf (s+2)%3 free to overwrite
  }

  // row i lives in the 16 lanes of one quad-group: reduce across them
  #pragma unroll
  for (int i = 0; i < 8; ++i){
    #pragma unroll
    for (int m = 1; m < 16; m <<= 1){
      vpos[i] = fmaxf(vpos[i], __shfl_xor(vpos[i], m, 16));
      vneg[i] = fminf(vneg[i], __shfl_xor(vneg[i], m, 16));
    }
  }
  if (m16 == 0){
    #pragma unroll
    for (int i = 0; i < 8; ++i){
      const int row = WR0 + (i >> 2)*16 + quad*4 + (i & 3);
      ppos[blockIdx.y * NB + row] = vpos[i];
      pneg[blockIdx.y * NB + row] = vneg[i];
    }
  }
}

// ---- finalize (fused): 64 blocks x 128 rows -> atomic finish ---------------
extern "C" __global__ __launch_bounds__(128)
void fin_k(const float* __restrict__ ppos, const float* __restrict__ pneg,
           const float4* __restrict__ colp, float* __restrict__ gred,
           unsigned int* __restrict__ done, float* __restrict__ out)
{
  const int row = blockIdx.x * 128 + threadIdx.x;
  float up = NEGINF, un = POSINF;
  #pragma unroll
  for (int c = 0; c < NCHUNK; ++c){
    up = fmaxf(up, ppos[c * NB + row]);
    un = fminf(un, pneg[c * NB + row]);
  }
  const bool hp = (up > NEGINF);
  const bool hn = (un < POSINF);
  const float pi = colp[row].y;
  float dp = 0.0f, dn = 0.0f;
  // arccosh(1+t) = log1p(t + sqrt(t*(t+2))), t clamped at 1e-7 (matches ref)
  if (hp){ float t = fmaxf(2.0f * up * pi, 1e-7f); dp = log1pf(t + sqrtf(t * (t + 2.0f))); }
  if (hn){ float t = fmaxf(2.0f * un * pi, 1e-7f); dn = log1pf(t + sqrtf(t * (t + 2.0f))); }
  float lsum = (hp && hn) ? fmaxf(dp - dn + 0.5f, 0.0f) : 0.0f;
  float lcnt = (hp && hn) ? 1.0f : 0.0f;
  #pragma unroll
  for (int m = 1; m < 64; m <<= 1){
    lsum += __shfl_xor(lsum, m, 64);
    lcnt += __shfl_xor(lcnt, m, 64);
  }
  __shared__ float2 s_p[2];
  if ((threadIdx.x & 63) == 0) s_p[threadIdx.x >> 6] = make_float2(lsum, lcnt);
  __syncthreads();
  if (threadIdx.x == 0){
    const float bs = s_p[0].x + s_p[1].x;
    const float bc = s_p[0].y + s_p[1].y;
    atomicAdd(&gred[0], bs);
    atomicAdd(&gred[1], bc);
    __threadfence();
    const unsigned int prev = atomicAdd(done, 1u);
    if (prev == 63u){                      // last block: all adds visible
      __threadfence();
      const float s = atomicAdd(&gred[0], 0.0f);   // read via atomic (L2)
      const float c = atomicAdd(&gred[1], 0.0f);
      out[0] = (c > 0.0f) ? (s / c) : 0.0f;
    }
  }
}

extern "C" void kernel_launch(void* const* d_in, const int* in_sizes, int n_in,
                              void* d_out, int out_size, void* d_ws, size_t ws_size,
                              hipStream_t stream)
{
  const float* x  = (const float*)d_in[0];
  const int* lab  = (const int*)d_in[1];
  char* ws = (char*)d_ws;
  u16*    xb   = (u16*)ws;                                        // 2 MB
  float4* colp = (float4*)(ws + (size_t)2*1024*1024);             // 128 KB
  float*  ppos = (float*)(ws + (size_t)2*1024*1024 + 128*1024);   // 512 KB
  float*  pneg = (float*)(ws + (size_t)2*1024*1024 + 128*1024 + 512*1024); // 512 KB
  float*  gred = (float*)(ws + (size_t)2*1024*1024 + 128*1024 + 1024*1024); // 8 B
  unsigned int* done = (unsigned int*)(ws + (size_t)2*1024*1024 + 128*1024
                                          + 1024*1024 + 64);      // 4 B

  hipLaunchKernelGGL(prep_k, dim3(1024), dim3(256), 0, stream, x, lab, xb, colp,
                     gred, done);
  hipLaunchKernelGGL(gram_k, dim3(64, NCHUNK), dim3(256), 0, stream,
                     xb, colp, ppos, pneg);
  hipLaunchKernelGGL(fin_k, dim3(64), dim3(128), 0, stream, ppos, pneg, colp,
                     gred, done, (float*)d_out);
}